// Round 3
// baseline (400.459 us; speedup 1.0000x reference)
//
#include <hip/hip_runtime.h>
#include <hip/hip_bf16.h>

#define D_MODEL 256
#define HEADS 4
#define HD 64
#define BATCH 4
#define SEQ 4096
#define NPOS (BATCH*SEQ)          // 16384 positions
#define SCALE_LOG2 0.18033688011112042f  // log2(e)/8, folded into q projection

typedef __attribute__((ext_vector_type(4))) float floatx4;
typedef __attribute__((ext_vector_type(8))) short bf16x8;
typedef __attribute__((ext_vector_type(4))) short bf16x4;
typedef __attribute__((ext_vector_type(4))) unsigned short ushortx4;

__device__ __forceinline__ float bf2f(unsigned short b) {
    return __uint_as_float(((unsigned int)b) << 16);
}
__device__ __forceinline__ unsigned short f2bf(float f) {
    unsigned int u = __float_as_uint(f);
    return (unsigned short)((u + 0x7fffu + ((u >> 16) & 1u)) >> 16);
}
__device__ __forceinline__ bf16x4 pack_bf16x4(float a, float b, float c, float d) {
    __hip_bfloat162 lo = __float22bfloat162_rn(float2{a, b});
    __hip_bfloat162 hi = __float22bfloat162_rn(float2{c, d});
    union { __hip_bfloat162 h2[2]; bf16x4 v; } u;
    u.h2[0] = lo; u.h2[1] = hi;
    return u.v;
}
__device__ __forceinline__ bf16x8 pack_bf16x8(floatx4 a, floatx4 b) {
    union { bf16x4 h[2]; bf16x8 v; } u;
    u.h[0] = pack_bf16x4(a[0], a[1], a[2], a[3]);
    u.h[1] = pack_bf16x4(b[0], b[1], b[2], b[3]);
    return u.v;
}
#define MFMA(a,b,c) __builtin_amdgcn_mfma_f32_16x16x32_bf16((a),(b),(c),0,0,0)

// ---------------------------------------------------------------------------
// QKV projection: out = W[256x256] @ X[b][256][SEQ] + bias.
// mode 0/1: q/k -> [bh][n][64] via LDS-staged coalesced epilogue (mode 0
//           also folds in softmax scale log2(e)/8)
// mode 2:   v -> [bh][64][m] direct epilogue (32B-chunk coalesced)
// grid (2, SEQ/128, B), block 256.
// ---------------------------------------------------------------------------
__global__ __launch_bounds__(256) void proj_qkv(
        const float* __restrict__ W, const float* __restrict__ bias,
        const float* __restrict__ X, unsigned short* __restrict__ out, int mode)
{
    __shared__ unsigned short smem[128 * 80];   // lA(128x40) + lB(128x40); reused as stage[128][72]
    unsigned short (*lA)[40] = (unsigned short (*)[40])smem;
    unsigned short (*lB)[40] = (unsigned short (*)[40])(smem + 128 * 40);
    unsigned short (*stage)[72] = (unsigned short (*)[72])smem;
    const int t = threadIdx.x;
    const int lane = t & 63, wid = t >> 6;
    const int wm = wid >> 1, wn = wid & 1;
    const int lrow = lane & 15, quad = lane >> 4;
    const int ob = blockIdx.x * 128;
    const int n0 = blockIdx.y * 128;
    const int b  = blockIdx.z;

    floatx4 acc[4][4];
#pragma unroll
    for (int i = 0; i < 4; ++i)
#pragma unroll
        for (int j = 0; j < 4; ++j) acc[i][j] = (floatx4){0.f,0.f,0.f,0.f};

    for (int kc = 0; kc < 8; ++kc) {
        const int k0 = kc * 32;
#pragma unroll
        for (int r = 0; r < 4; ++r) {               // stage W -> lA (k-contig)
            int linear = r * 1024 + t * 4;
            int row = linear >> 5, col = linear & 31;
            const float4 w4 = *(const float4*)&W[(size_t)(ob + row) * 256 + k0 + col];
            ushortx4 s4 = { f2bf(w4.x), f2bf(w4.y), f2bf(w4.z), f2bf(w4.w) };
            *(ushortx4*)&lA[row][col] = s4;
        }
#pragma unroll
        for (int r = 0; r < 4; ++r) {               // stage X^T -> lB (transpose)
            int linear = r * 1024 + t * 4;
            int ch = linear >> 7, nn = linear & 127;
            const float4 x4 = *(const float4*)&X[((size_t)b * 256 + k0 + ch) * SEQ + n0 + nn];
            lB[nn + 0][ch] = f2bf(x4.x);
            lB[nn + 1][ch] = f2bf(x4.y);
            lB[nn + 2][ch] = f2bf(x4.z);
            lB[nn + 3][ch] = f2bf(x4.w);
        }
        __syncthreads();
        bf16x8 aF[4], bF[4];
        const int kq = quad * 8;
#pragma unroll
        for (int mt = 0; mt < 4; ++mt)
            aF[mt] = *(const bf16x8*)&lA[wm*64 + mt*16 + lrow][kq];
#pragma unroll
        for (int nt = 0; nt < 4; ++nt)
            bF[nt] = *(const bf16x8*)&lB[wn*64 + nt*16 + lrow][kq];
#pragma unroll
        for (int mt = 0; mt < 4; ++mt)
#pragma unroll
            for (int nt = 0; nt < 4; ++nt)
                acc[mt][nt] = MFMA(aF[mt], bF[nt], acc[mt][nt]);
        __syncthreads();
    }
    const float osc = (mode == 0) ? SCALE_LOG2 : 1.0f;
    if (mode == 2) {
        // v: direct epilogue, [bh][d][m]: 32B contiguous per quad-group
#pragma unroll
        for (int mt = 0; mt < 4; ++mt) {
#pragma unroll
            for (int j = 0; j < 4; ++j) {
                int o = ob + wm*64 + mt*16 + quad*4 + j;
                float bv = bias[o];
                int d = o >> 2, h = o & 3;
#pragma unroll
                for (int nt = 0; nt < 4; ++nt) {
                    int n = n0 + wn*64 + nt*16 + lrow;
                    out[((size_t)(b*HEADS + h) * HD + d) * SEQ + n] = f2bf(acc[mt][nt][j] + bv);
                }
            }
        }
        return;
    }
    // q/k: LDS-staged epilogue -> [bh][n][64] with 32B-contiguous chunks
    for (int half = 0; half < 2; ++half) {
        __syncthreads();
        if (wm == half) {
            // h = o&3 = j ; dL = mt*4+quad ; col = j*16 + dL
#pragma unroll
            for (int mt = 0; mt < 4; ++mt)
#pragma unroll
                for (int j = 0; j < 4; ++j) {
                    int o = ob + half*64 + mt*16 + quad*4 + j;
                    float bv = bias[o];
                    int col = j*16 + mt*4 + quad;
#pragma unroll
                    for (int nt = 0; nt < 4; ++nt) {
                        int n = wn*64 + nt*16 + lrow;
                        stage[n][col] = f2bf((acc[mt][nt][j] + bv) * osc);
                    }
                }
        }
        __syncthreads();
        // write 128 n x 4 h x 16 d-shorts (2 b128 chunks each)
#pragma unroll
        for (int i = 0; i < 4; ++i) {
            int c = i * 256 + t;
            int n = c >> 3, h = (c >> 1) & 3, sub = c & 1;
            bf16x8 val = *(const bf16x8*)&stage[n][h*16 + sub*8];
            int d0 = (ob >> 2) + half*16 + sub*8;
            *(bf16x8*)&out[((size_t)(b*HEADS + h) * SEQ + n0 + n) * HD + d0] = val;
        }
    }
}

// ---------------------------------------------------------------------------
// Flash attention, transposed-softmax, all-K=32-MFMA formulation.
// grid (SEQ/128, 16), block 256: wave handles 32 q-rows (2 n-frags), 64-m tiles.
// K is staged into LDS with PERMUTED rows so that the 16x16 S^T C-layout
// output is natively the B-fragment (k=quad*8+j) of the K=32 PV MFMA:
//   within a 32-m chunk: tile AB=(m'>>2)&1, local row=(m'>>3)*4+(m'&3).
// Output written to attn' layout [h*BATCH+b][n][d] (contiguous) via LDS stage.
// ---------------------------------------------------------------------------
__global__ __launch_bounds__(256) void flash_attn(
        const unsigned short* __restrict__ q,
        const unsigned short* __restrict__ k,
        const unsigned short* __restrict__ v,
        unsigned short* __restrict__ attnp)
{
    __shared__ unsigned short smem[128 * 72];  // lK(64x72) + lV(64x72), reused as stage[128][72]
    unsigned short (*lK)[72] = (unsigned short (*)[72])smem;
    unsigned short (*lV)[72] = (unsigned short (*)[72])(smem + 64 * 72);
    unsigned short (*stage)[72] = (unsigned short (*)[72])smem;
    const int t = threadIdx.x, lane = t & 63, wid = t >> 6;
    const int lrow = lane & 15, quad = lane >> 4;
    const int qt = blockIdx.x, bh = blockIdx.y;
    const int b = bh >> 2, h = bh & 3;
    const int r0 = qt * 128 + wid * 32;        // wave's q-row base (32 rows)

    // Q fragments: B-operand of S^T, k=d=quad*8+i, col n=lrow (per n-half)
    bf16x8 qf[2][2];
#pragma unroll
    for (int nh = 0; nh < 2; ++nh) {
        const size_t base = ((size_t)bh * SEQ + r0 + nh*16 + lrow) * HD;
        qf[nh][0] = *(const bf16x8*)&q[base + quad * 8];
        qf[nh][1] = *(const bf16x8*)&q[base + 32 + quad * 8];
    }
    float ls[2] = {0.f, 0.f};
    floatx4 oacc[2][4];
#pragma unroll
    for (int nh = 0; nh < 2; ++nh)
#pragma unroll
        for (int i = 0; i < 4; ++i) oacc[nh][i] = (floatx4){0.f,0.f,0.f,0.f};

#pragma unroll 1
    for (int it = 0; it < SEQ / 64; ++it) {
        const int m0 = it * 64;
        __syncthreads();
#pragma unroll
        for (int r = 0; r < 2; ++r) {          // stage K (permuted rows) and V
            int linear = r * 256 + t;
            int mm = linear >> 3, cg = (linear & 7) * 8;
            int chunk = mm >> 5, mp = mm & 31;
            int krow = (chunk << 5) + ((mp & 4) << 2) + ((mp >> 3) << 2) + (mp & 3);
            *(bf16x8*)&lK[krow][cg] = *(const bf16x8*)&k[((size_t)bh * SEQ + m0 + mm) * HD + cg];
            *(bf16x8*)&lV[mm][cg]   = *(const bf16x8*)&v[((size_t)bh * HD + mm) * SEQ + m0 + cg];
        }
        __syncthreads();

        bf16x8 pf8[2][2];                      // [chunk][nh] — P^T as x32 B-fragments
#pragma unroll
        for (int chunk = 0; chunk < 2; ++chunk) {
            floatx4 sa[2][2];                  // [AB][nh]
#pragma unroll
            for (int AB = 0; AB < 2; ++AB) {
                sa[AB][0] = (floatx4){0.f,0.f,0.f,0.f};
                sa[AB][1] = (floatx4){0.f,0.f,0.f,0.f};
#pragma unroll
                for (int kc = 0; kc < 2; ++kc) {
                    bf16x8 kf = *(const bf16x8*)&lK[chunk*32 + AB*16 + lrow][kc*32 + quad*8];
                    sa[AB][0] = MFMA(kf, qf[0][kc], sa[AB][0]);
                    sa[AB][1] = MFMA(kf, qf[1][kc], sa[AB][1]);
                }
            }
#pragma unroll
            for (int nh = 0; nh < 2; ++nh) {
                floatx4 ea, eb;
#pragma unroll
                for (int i = 0; i < 4; ++i) { ea[i] = exp2f(sa[0][nh][i]); eb[i] = exp2f(sa[1][nh][i]); }
                ls[nh] += (ea[0]+ea[1]) + (ea[2]+ea[3]) + (eb[0]+eb[1]) + (eb[2]+eb[3]);
                pf8[chunk][nh] = pack_bf16x8(ea, eb);
            }
        }
        // O^T += V^T · P^T, all K=32: A = V^T[d][m] (k=quad*8+i), B = pf8
#pragma unroll
        for (int chunk = 0; chunk < 2; ++chunk) {
#pragma unroll
            for (int dt = 0; dt < 4; ++dt) {
                bf16x8 vf = *(const bf16x8*)&lV[dt*16 + lrow][chunk*32 + quad*8];
                oacc[0][dt] = MFMA(vf, pf8[chunk][0], oacc[0][dt]);
                oacc[1][dt] = MFMA(vf, pf8[chunk][1], oacc[1][dt]);
            }
        }
    }
    float inv[2];
#pragma unroll
    for (int nh = 0; nh < 2; ++nh) {
        float s = ls[nh];
        s += __shfl_xor(s, 16);
        s += __shfl_xor(s, 32);
        inv[nh] = 1.0f / s;
    }
    // epilogue: stage O^T (row d = quad*4+j, col n = lrow) -> stage[n][d]
    __syncthreads();
#pragma unroll
    for (int nh = 0; nh < 2; ++nh)
#pragma unroll
        for (int dt = 0; dt < 4; ++dt)
#pragma unroll
            for (int j = 0; j < 4; ++j)
                stage[wid*32 + nh*16 + lrow][dt*16 + quad*4 + j] = f2bf(oacc[nh][dt][j] * inv[nh]);
    __syncthreads();
    // coalesced write: attn'[(h*BATCH+b)][n][d] — 128 rows x 128 B contiguous
    const size_t obase = ((size_t)(h * BATCH + b) * SEQ + qt * 128) * HD;
#pragma unroll
    for (int i = 0; i < 4; ++i) {
        int c = i * 256 + t;
        int row = c >> 3, sub = c & 7;
        *(bf16x8*)&attnp[obase + (size_t)row * HD + sub * 8] = *(const bf16x8*)&stage[row][sub*8];
    }
}

// ---------------------------------------------------------------------------
// prep: column-permuted bf16 copy of merge_w for the attn' layout:
// W'[o][c'] = W[o][(c'&63)*4 + (c'>>6)], c' = h*64+d.
// ---------------------------------------------------------------------------
__global__ __launch_bounds__(256) void prep_wmerge(
        const float* __restrict__ W, unsigned short* __restrict__ Wp)
{
    int i = blockIdx.x * 256 + threadIdx.x;
    int o = i >> 8, cp = i & 255;
    Wp[i] = f2bf(W[(size_t)o * 256 + ((cp & 63) << 2) + (cp >> 6)]);
}

// ---------------------------------------------------------------------------
// GEMM (activations x W^T): out[pos][O] = act[pos][K] @ W[O][K]^T + bias
// mode 0: merge — act = attn' [hb][n][64] (K=256 via c'=h*64+d), W = Wp bf16
// mode 1: mlp1  — K=512: k<256 from x f32 (transpose), k>=256 from message
// grid (O/128, NPOS/128), block 256.
// ---------------------------------------------------------------------------
__global__ __launch_bounds__(256) void gemm_act_w(
        const unsigned short* __restrict__ actA, const float* __restrict__ X,
        const float* __restrict__ Wf, const unsigned short* __restrict__ Wbf,
        const float* __restrict__ bias,
        unsigned short* __restrict__ out, int mode)
{
    __shared__ unsigned short lA[128][40];  // activations [pos][k]
    __shared__ unsigned short lB[128][40];  // W [o][k]
    const int t = threadIdx.x;
    const int lane = t & 63, wid = t >> 6;
    const int wm = wid >> 1, wn = wid & 1;
    const int lrow = lane & 15, quad = lane >> 4;
    const int o0 = blockIdx.x * 128;
    const int p0 = blockIdx.y * 128;
    const int b = p0 >> 12, n0 = p0 & (SEQ - 1);
    const int K = mode ? 512 : 256;
    const int O = mode ? 512 : 256;

    floatx4 acc[4][4];
#pragma unroll
    for (int i = 0; i < 4; ++i)
#pragma unroll
        for (int j = 0; j < 4; ++j) acc[i][j] = (floatx4){0.f,0.f,0.f,0.f};

    for (int k0 = 0; k0 < K; k0 += 32) {
        if (mode == 0) {
            // A from attn' [hb][n][64]: h = k0>>6, d0 = k0&63
            int hq = k0 >> 6, d0 = k0 & 63;
            const size_t abase = ((size_t)(hq * BATCH + b) * SEQ + n0) * HD + d0;
#pragma unroll
            for (int r = 0; r < 2; ++r) {
                int linear = r * 256 + t;
                int row = linear >> 2, cg = (linear & 3) * 8;
                *(bf16x8*)&lA[row][cg] = *(const bf16x8*)&actA[abase + (size_t)row * HD + cg];
            }
#pragma unroll
            for (int r = 0; r < 2; ++r) {       // W' bf16, coalesced
                int linear = r * 256 + t;
                int row = linear >> 2, cg = (linear & 3) * 8;
                *(bf16x8*)&lB[row][cg] = *(const bf16x8*)&Wbf[(size_t)(o0 + row) * 256 + k0 + cg];
            }
        } else {
            if (k0 < 256) {                     // x f32: transpose stage
#pragma unroll
                for (int r = 0; r < 4; ++r) {
                    int linear = r * 1024 + t * 4;
                    int ch = linear >> 7, nn = linear & 127;
                    const float4 x4 = *(const float4*)&X[((size_t)b * 256 + k0 + ch) * SEQ + n0 + nn];
                    lA[nn + 0][ch] = f2bf(x4.x);
                    lA[nn + 1][ch] = f2bf(x4.y);
                    lA[nn + 2][ch] = f2bf(x4.z);
                    lA[nn + 3][ch] = f2bf(x4.w);
                }
            } else {
#pragma unroll
                for (int r = 0; r < 2; ++r) {
                    int linear = r * 256 + t;
                    int row = linear >> 2, cg = (linear & 3) * 8;
                    *(bf16x8*)&lA[row][cg] = *(const bf16x8*)&actA[(size_t)(p0 + row) * 256 + (k0 - 256) + cg];
                }
            }
#pragma unroll
            for (int r = 0; r < 4; ++r) {       // stage W f32
                int linear = r * 1024 + t * 4;
                int row = linear >> 5, col = linear & 31;
                const float4 w4 = *(const float4*)&Wf[(size_t)(o0 + row) * K + k0 + col];
                ushortx4 s4 = { f2bf(w4.x), f2bf(w4.y), f2bf(w4.z), f2bf(w4.w) };
                *(ushortx4*)&lB[row][col] = s4;
            }
        }
        __syncthreads();
        bf16x8 aF[4], bF[4];
        const int kq = quad * 8;
#pragma unroll
        for (int mt = 0; mt < 4; ++mt)
            aF[mt] = *(const bf16x8*)&lA[wm*64 + mt*16 + lrow][kq];
#pragma unroll
        for (int nt = 0; nt < 4; ++nt)
            bF[nt] = *(const bf16x8*)&lB[wn*64 + nt*16 + lrow][kq];
#pragma unroll
        for (int mt = 0; mt < 4; ++mt)
#pragma unroll
            for (int nt = 0; nt < 4; ++nt)
                acc[mt][nt] = MFMA(aF[mt], bF[nt], acc[mt][nt]);
        __syncthreads();
    }
    // epilogue: D row = pos, col = o; out[pos][O] bf16
#pragma unroll
    for (int nt = 0; nt < 4; ++nt) {
        int o = o0 + wn*64 + nt*16 + lrow;
        float bv = bias[o];
#pragma unroll
        for (int mt = 0; mt < 4; ++mt)
#pragma unroll
            for (int j = 0; j < 4; ++j) {
                int pos = p0 + wm*64 + mt*16 + quad*4 + j;
                out[(size_t)pos * O + o] = f2bf(acc[mt][nt][j] + bv);
            }
    }
}

// ---------------------------------------------------------------------------
// BN stats: per-channel sum/sumsq over 16384 positions. grid 128, block 256.
// ---------------------------------------------------------------------------
__global__ __launch_bounds__(256) void bn_stats(
        const unsigned short* __restrict__ h1,
        float* __restrict__ sums, float* __restrict__ sumsq)
{
    const int t = threadIdx.x;
    const int r0 = blockIdx.x * 128;
    const unsigned int* p32 = (const unsigned int*)h1;
    float s0 = 0.f, s1 = 0.f, q0 = 0.f, q1 = 0.f;
    for (int r = 0; r < 128; ++r) {
        unsigned int u = p32[(size_t)(r0 + r) * 256 + t];
        float f0 = bf2f((unsigned short)(u & 0xffffu));
        float f1 = bf2f((unsigned short)(u >> 16));
        s0 += f0; q0 += f0 * f0;
        s1 += f1; q1 += f1 * f1;
    }
    atomicAdd(&sums[2*t],   s0);
    atomicAdd(&sums[2*t+1], s1);
    atomicAdd(&sumsq[2*t],   q0);
    atomicAdd(&sumsq[2*t+1], q1);
}

__global__ __launch_bounds__(256) void bn_final(
        const float* __restrict__ sums, const float* __restrict__ sumsq,
        const float* __restrict__ gamma, const float* __restrict__ beta,
        float* __restrict__ scale, float* __restrict__ shift)
{
    int c = blockIdx.x * 256 + threadIdx.x;
    if (c < 512) {
        float mean = sums[c] * (1.0f / NPOS);
        float var  = sumsq[c] * (1.0f / NPOS) - mean * mean;
        float sc = gamma[c] * rsqrtf(var + 1e-5f);
        scale[c] = sc;
        shift[c] = beta[c] - mean * sc;
    }
}

// ---------------------------------------------------------------------------
// mlp2: out[b][o][n] f32 = W[256][512] @ relu(bn(h1))[pos][512]^T + bias
// grid (2, NPOS/128), block 256.
// ---------------------------------------------------------------------------
__global__ __launch_bounds__(256) void gemm_mlp2(
        const float* __restrict__ W, const unsigned short* __restrict__ h1,
        const float* __restrict__ bias,
        const float* __restrict__ bnscale, const float* __restrict__ bnshift,
        float* __restrict__ out)
{
    __shared__ unsigned short lA[128][40];  // W [o][k]
    __shared__ unsigned short lB[128][40];  // act [pos][k]
    __shared__ float sSc[512], sSh[512];
    const int t = threadIdx.x;
    const int lane = t & 63, wid = t >> 6;
    const int wm = wid >> 1, wn = wid & 1;
    const int lrow = lane & 15, quad = lane >> 4;
    const int o0 = blockIdx.x * 128;
    const int p0 = blockIdx.y * 128;

    sSc[t] = bnscale[t];  sSc[t + 256] = bnscale[t + 256];
    sSh[t] = bnshift[t];  sSh[t + 256] = bnshift[t + 256];
    __syncthreads();

    floatx4 acc[4][4];
#pragma unroll
    for (int i = 0; i < 4; ++i)
#pragma unroll
        for (int j = 0; j < 4; ++j) acc[i][j] = (floatx4){0.f,0.f,0.f,0.f};

    for (int k0 = 0; k0 < 512; k0 += 32) {
#pragma unroll
        for (int r = 0; r < 4; ++r) {           // stage W
            int linear = r * 1024 + t * 4;
            int row = linear >> 5, col = linear & 31;
            const float4 w4 = *(const float4*)&W[(size_t)(o0 + row) * 512 + k0 + col];
            ushortx4 s4 = { f2bf(w4.x), f2bf(w4.y), f2bf(w4.z), f2bf(w4.w) };
            *(ushortx4*)&lA[row][col] = s4;
        }
#pragma unroll
        for (int r = 0; r < 2; ++r) {           // stage h1 with BN+ReLU fused
            int linear = r * 256 + t;
            int row = linear >> 2, cg = (linear & 3) * 8;
            bf16x8 hv = *(const bf16x8*)&h1[(size_t)(p0 + row) * 512 + k0 + cg];
            unsigned short res[8];
#pragma unroll
            for (int i = 0; i < 8; ++i) {
                int c = k0 + cg + i;
                float f = bf2f((unsigned short)hv[i]);
                f = fmaxf(f * sSc[c] + sSh[c], 0.f);
                res[i] = f2bf(f);
            }
            *(bf16x8*)&lB[row][cg] = *(const bf16x8*)res;
        }
        __syncthreads();
        bf16x8 aF[4], bF[4];
        const int kq = quad * 8;
#pragma unroll
        for (int mt = 0; mt < 4; ++mt)
            aF[mt] = *(const bf16x8*)&lA[wm*64 + mt*16 + lrow][kq];
#pragma unroll
        for (int nt = 0; nt < 4; ++nt)
            bF[nt] = *(const bf16x8*)&lB[wn*64 + nt*16 + lrow][kq];
#pragma unroll
        for (int mt = 0; mt < 4; ++mt)
#pragma unroll
            for (int nt = 0; nt < 4; ++nt)
                acc[mt][nt] = MFMA(aF[mt], bF[nt], acc[mt][nt]);
        __syncthreads();
    }
    // epilogue: D row = o, col = pos; out[b][o][n] f32 (coalesced 64B groups)
#pragma unroll
    for (int mt = 0; mt < 4; ++mt)
#pragma unroll
        for (int j = 0; j < 4; ++j) {
            int o = o0 + wm*64 + mt*16 + quad*4 + j;
            float bv = bias[o];
#pragma unroll
            for (int nt = 0; nt < 4; ++nt) {
                int pos = p0 + wn*64 + nt*16 + lrow;
                int b = pos >> 12, n = pos & (SEQ - 1);
                out[((size_t)b * D_MODEL + o) * SEQ + n] = acc[mt][nt][j] + bv;
            }
        }
}

// ---------------------------------------------------------------------------
extern "C" void kernel_launch(void* const* d_in, const int* in_sizes, int n_in,
                              void* d_out, int out_size, void* d_ws, size_t ws_size,
                              hipStream_t stream)
{
    (void)in_sizes; (void)n_in; (void)out_size; (void)ws_size;
    const float* x        = (const float*)d_in[0];
    const float* source   = (const float*)d_in[1];
    const float* pq_w     = (const float*)d_in[2];
    const float* pq_b     = (const float*)d_in[3];
    const float* pk_w     = (const float*)d_in[4];
    const float* pk_b     = (const float*)d_in[5];
    const float* pv_w     = (const float*)d_in[6];
    const float* pv_b     = (const float*)d_in[7];
    const float* merge_w  = (const float*)d_in[8];
    const float* merge_b  = (const float*)d_in[9];
    const float* mlp1_w   = (const float*)d_in[10];
    const float* mlp1_b   = (const float*)d_in[11];
    const float* bn_gamma = (const float*)d_in[12];
    const float* bn_beta  = (const float*)d_in[13];
    const float* mlp2_w   = (const float*)d_in[14];
    const float* mlp2_b   = (const float*)d_in[15];
    float* out = (float*)d_out;

    char* ws = (char*)d_ws;
    unsigned short* q    = (unsigned short*)(ws);                 //  8 MB [bh][n][64]
    unsigned short* kk   = (unsigned short*)(ws + (8ull  << 20)); //  8 MB [bh][m][64]
    unsigned short* v    = (unsigned short*)(ws + (16ull << 20)); //  8 MB [bh][64][m]
    unsigned short* attn = (unsigned short*)(ws + (24ull << 20)); //  8 MB [hb][n][64]
    unsigned short* msg  = (unsigned short*)(ws + (32ull << 20)); //  8 MB [pos][256]
    unsigned short* h1   = (unsigned short*)(ws + (40ull << 20)); // 16 MB [pos][512]
    float* bn_sum   = (float*)(ws + (56ull << 20));
    float* bn_sumsq = bn_sum + 512;
    float* bn_scale = bn_sum + 1024;
    float* bn_shift = bn_sum + 1536;
    unsigned short* wmp = (unsigned short*)(ws + (57ull << 20));  // 128 KB W' bf16

    hipMemsetAsync(bn_sum, 0, 1024 * sizeof(float), stream);

    prep_wmerge<<<dim3(256), 256, 0, stream>>>(merge_w, wmp);
    proj_qkv<<<dim3(2, SEQ/128, BATCH), 256, 0, stream>>>(pq_w, pq_b, x,      q,  0);
    proj_qkv<<<dim3(2, SEQ/128, BATCH), 256, 0, stream>>>(pk_w, pk_b, source, kk, 1);
    proj_qkv<<<dim3(2, SEQ/128, BATCH), 256, 0, stream>>>(pv_w, pv_b, source, v,  2);
    flash_attn<<<dim3(SEQ/128, BATCH*HEADS), 256, 0, stream>>>(q, kk, v, attn);
    gemm_act_w<<<dim3(2, NPOS/128), 256, 0, stream>>>(attn, nullptr, nullptr, wmp, merge_b, msg, 0);
    gemm_act_w<<<dim3(4, NPOS/128), 256, 0, stream>>>(msg, x, mlp1_w, nullptr, mlp1_b, h1, 1);
    bn_stats<<<dim3(128), 256, 0, stream>>>(h1, bn_sum, bn_sumsq);
    bn_final<<<dim3(2), 256, 0, stream>>>(bn_sum, bn_sumsq, bn_gamma, bn_beta, bn_scale, bn_shift);
    gemm_mlp2<<<dim3(2, NPOS/128), 256, 0, stream>>>(mlp2_w, h1, mlp2_b, bn_scale, bn_shift, out);
}

// Round 4
// 343.813 us; speedup vs baseline: 1.1648x; 1.1648x over previous
//
#include <hip/hip_runtime.h>
#include <hip/hip_bf16.h>

#define D_MODEL 256
#define HEADS 4
#define HD 64
#define BATCH 4
#define SEQ 4096
#define NPOS (BATCH*SEQ)          // 16384 positions
#define SCALE_LOG2 0.18033688011112042f  // log2(e)/8, folded into q projection
#define MCHUNKS 2                 // flash m-split (partials add; no online max)

typedef __attribute__((ext_vector_type(4))) float floatx4;
typedef __attribute__((ext_vector_type(8))) short bf16x8;
typedef __attribute__((ext_vector_type(4))) short bf16x4;
typedef __attribute__((ext_vector_type(4))) unsigned short ushortx4;

__device__ __forceinline__ float bf2f(unsigned short b) {
    return __uint_as_float(((unsigned int)b) << 16);
}
__device__ __forceinline__ unsigned short f2bf(float f) {
    unsigned int u = __float_as_uint(f);
    return (unsigned short)((u + 0x7fffu + ((u >> 16) & 1u)) >> 16);
}
__device__ __forceinline__ bf16x4 pack_bf16x4(float a, float b, float c, float d) {
    __hip_bfloat162 lo = __float22bfloat162_rn(float2{a, b});
    __hip_bfloat162 hi = __float22bfloat162_rn(float2{c, d});
    union { __hip_bfloat162 h2[2]; bf16x4 v; } u;
    u.h2[0] = lo; u.h2[1] = hi;
    return u.v;
}
__device__ __forceinline__ bf16x8 pack_bf16x8(floatx4 a, floatx4 b) {
    union { bf16x4 h[2]; bf16x8 v; } u;
    u.h[0] = pack_bf16x4(a[0], a[1], a[2], a[3]);
    u.h[1] = pack_bf16x4(b[0], b[1], b[2], b[3]);
    return u.v;
}
#define MFMA(a,b,c) __builtin_amdgcn_mfma_f32_16x16x32_bf16((a),(b),(c),0,0,0)

// ---------------------------------------------------------------------------
// Merged QKV projection: one launch, grid (6, SEQ/128, B), block 256.
// blockIdx.x: mode = x>>1 (0=q,1=k,2=v), ob = (x&1)*128.
// q/k -> [bh][n][64] (q also scaled by log2(e)/8); v -> [bh][64][m].
// ---------------------------------------------------------------------------
__global__ __launch_bounds__(256) void proj_qkv_all(
        const float* __restrict__ Wq, const float* __restrict__ bq,
        const float* __restrict__ Wk, const float* __restrict__ bk,
        const float* __restrict__ Wv, const float* __restrict__ bv,
        const float* __restrict__ xin, const float* __restrict__ src,
        unsigned short* __restrict__ qo, unsigned short* __restrict__ ko,
        unsigned short* __restrict__ vo)
{
    __shared__ unsigned short smem[128 * 80];   // lA(128x40)+lB(128x40); reused as stage[128][72]
    unsigned short (*lA)[40] = (unsigned short (*)[40])smem;
    unsigned short (*lB)[40] = (unsigned short (*)[40])(smem + 128 * 40);
    unsigned short (*stage)[72] = (unsigned short (*)[72])smem;
    const int t = threadIdx.x;
    const int lane = t & 63, wid = t >> 6;
    const int wm = wid >> 1, wn = wid & 1;
    const int lrow = lane & 15, quad = lane >> 4;
    const int mode = blockIdx.x >> 1;
    const int ob = (blockIdx.x & 1) * 128;
    const int n0 = blockIdx.y * 128;
    const int b  = blockIdx.z;
    const float* W    = (mode == 0) ? Wq : (mode == 1) ? Wk : Wv;
    const float* bias = (mode == 0) ? bq : (mode == 1) ? bk : bv;
    const float* X    = (mode == 0) ? xin : src;
    unsigned short* out = (mode == 0) ? qo : (mode == 1) ? ko : vo;

    floatx4 acc[4][4];
#pragma unroll
    for (int i = 0; i < 4; ++i)
#pragma unroll
        for (int j = 0; j < 4; ++j) acc[i][j] = (floatx4){0.f,0.f,0.f,0.f};

    for (int kc = 0; kc < 8; ++kc) {
        const int k0 = kc * 32;
#pragma unroll
        for (int r = 0; r < 4; ++r) {               // stage W -> lA (k-contig)
            int linear = r * 1024 + t * 4;
            int row = linear >> 5, col = linear & 31;
            const float4 w4 = *(const float4*)&W[(size_t)(ob + row) * 256 + k0 + col];
            ushortx4 s4 = { f2bf(w4.x), f2bf(w4.y), f2bf(w4.z), f2bf(w4.w) };
            *(ushortx4*)&lA[row][col] = s4;
        }
#pragma unroll
        for (int r = 0; r < 4; ++r) {               // stage X^T -> lB (transpose)
            int linear = r * 1024 + t * 4;
            int ch = linear >> 7, nn = linear & 127;
            const float4 x4 = *(const float4*)&X[((size_t)b * 256 + k0 + ch) * SEQ + n0 + nn];
            lB[nn + 0][ch] = f2bf(x4.x);
            lB[nn + 1][ch] = f2bf(x4.y);
            lB[nn + 2][ch] = f2bf(x4.z);
            lB[nn + 3][ch] = f2bf(x4.w);
        }
        __syncthreads();
        bf16x8 aF[4], bF[4];
        const int kq = quad * 8;
#pragma unroll
        for (int mt = 0; mt < 4; ++mt)
            aF[mt] = *(const bf16x8*)&lA[wm*64 + mt*16 + lrow][kq];
#pragma unroll
        for (int nt = 0; nt < 4; ++nt)
            bF[nt] = *(const bf16x8*)&lB[wn*64 + nt*16 + lrow][kq];
#pragma unroll
        for (int mt = 0; mt < 4; ++mt)
#pragma unroll
            for (int nt = 0; nt < 4; ++nt)
                acc[mt][nt] = MFMA(aF[mt], bF[nt], acc[mt][nt]);
        __syncthreads();
    }
    const float osc = (mode == 0) ? SCALE_LOG2 : 1.0f;
    if (mode == 2) {
        // v: direct epilogue, [bh][d][m]: 32B contiguous per quad-group
#pragma unroll
        for (int mt = 0; mt < 4; ++mt) {
#pragma unroll
            for (int j = 0; j < 4; ++j) {
                int o = ob + wm*64 + mt*16 + quad*4 + j;
                float bvv = bias[o];
                int d = o >> 2, h = o & 3;
#pragma unroll
                for (int nt = 0; nt < 4; ++nt) {
                    int n = n0 + wn*64 + nt*16 + lrow;
                    out[((size_t)(b*HEADS + h) * HD + d) * SEQ + n] = f2bf(acc[mt][nt][j] + bvv);
                }
            }
        }
        return;
    }
    // q/k: LDS-staged epilogue -> [bh][n][64] with 16B-contiguous chunks
    for (int half = 0; half < 2; ++half) {
        __syncthreads();
        if (wm == half) {
#pragma unroll
            for (int mt = 0; mt < 4; ++mt)
#pragma unroll
                for (int j = 0; j < 4; ++j) {
                    int o = ob + half*64 + mt*16 + quad*4 + j;
                    float bvv = bias[o];
                    int col = j*16 + mt*4 + quad;
#pragma unroll
                    for (int nt = 0; nt < 4; ++nt) {
                        int n = wn*64 + nt*16 + lrow;
                        stage[n][col] = f2bf((acc[mt][nt][j] + bvv) * osc);
                    }
                }
        }
        __syncthreads();
#pragma unroll
        for (int i = 0; i < 4; ++i) {
            int c = i * 256 + t;
            int n = c >> 3, h = (c >> 1) & 3, sub = c & 1;
            bf16x8 val = *(const bf16x8*)&stage[n][h*16 + sub*8];
            int d0 = (ob >> 2) + half*16 + sub*8;
            *(bf16x8*)&out[((size_t)(b*HEADS + h) * SEQ + n0 + n) * HD + d0] = val;
        }
    }
}

// ---------------------------------------------------------------------------
// Flash attention, transposed-softmax, m-split, double-buffered LDS.
// grid (SEQ/128, 16*MCHUNKS), block 256: wave = 32 q-rows; block covers 2048 m.
// One barrier per m-tile iteration; K/V tile it+1 prefetched into registers
// while tile it computes, then written to the other LDS buffer.
// Partial O (f32) and partial denom l are written per chunk; no online max.
// ---------------------------------------------------------------------------
__global__ __launch_bounds__(256, 4) void flash_attn(
        const unsigned short* __restrict__ q,
        const unsigned short* __restrict__ k,
        const unsigned short* __restrict__ v,
        float* __restrict__ poO, float* __restrict__ pol)
{
    __shared__ unsigned short smem[2][9216];   // per buf: lK 64x72 then lV 64x72
    const int t = threadIdx.x, lane = t & 63, wid = t >> 6;
    const int lrow = lane & 15, quad = lane >> 4;
    const int qt = blockIdx.x;
    const int bh = blockIdx.y & 15, chunk = blockIdx.y >> 4;
    const int hb = (bh & 3) * BATCH + (bh >> 2);   // h*BATCH+b for attn' order
    const int r0 = qt * 128 + wid * 32;

    bf16x8 qf[2][2];
#pragma unroll
    for (int nh = 0; nh < 2; ++nh) {
        const size_t base = ((size_t)bh * SEQ + r0 + nh*16 + lrow) * HD;
        qf[nh][0] = *(const bf16x8*)&q[base + quad * 8];
        qf[nh][1] = *(const bf16x8*)&q[base + 32 + quad * 8];
    }
    // staging coords (2 vectors per thread)
    int mmv[2], cgv[2], krv[2];
#pragma unroll
    for (int r = 0; r < 2; ++r) {
        int linear = r * 256 + t;
        int mm = linear >> 3, cg = (linear & 7) * 8;
        int c2 = mm >> 5, mp = mm & 31;
        mmv[r] = mm; cgv[r] = cg;
        krv[r] = (c2 << 5) + ((mp & 4) << 2) + ((mp >> 3) << 2) + (mp & 3);
    }
    const size_t kbase = ((size_t)bh * SEQ + chunk * (SEQ/MCHUNKS));
    const size_t vbase = (size_t)bh * HD;
    const int moff = chunk * (SEQ/MCHUNKS);
    const int NIT = SEQ / MCHUNKS / 64;

    float ls[2] = {0.f, 0.f};
    floatx4 oacc[2][4];
#pragma unroll
    for (int nh = 0; nh < 2; ++nh)
#pragma unroll
        for (int i = 0; i < 4; ++i) oacc[nh][i] = (floatx4){0.f,0.f,0.f,0.f};

    // prologue: stage tile 0 into buf 0
    {
        bf16x8 pk[2], pv[2];
#pragma unroll
        for (int r = 0; r < 2; ++r) {
            pk[r] = *(const bf16x8*)&k[(kbase + mmv[r]) * HD + cgv[r]];
            pv[r] = *(const bf16x8*)&v[(vbase + mmv[r]) * SEQ + moff + cgv[r]];
        }
#pragma unroll
        for (int r = 0; r < 2; ++r) {
            *(bf16x8*)&smem[0][krv[r]*72 + cgv[r]]        = pk[r];
            *(bf16x8*)&smem[0][4608 + mmv[r]*72 + cgv[r]] = pv[r];
        }
    }
    __syncthreads();

    int p = 0;
#pragma unroll 1
    for (int it = 0; it < NIT; ++it) {
        bf16x8 pk[2], pv[2];
        const bool pre = (it + 1 < NIT);
        if (pre) {
            const int m1 = (it + 1) * 64;
#pragma unroll
            for (int r = 0; r < 2; ++r) {
                pk[r] = *(const bf16x8*)&k[(kbase + m1 + mmv[r]) * HD + cgv[r]];
                pv[r] = *(const bf16x8*)&v[(vbase + mmv[r]) * SEQ + moff + m1 + cgv[r]];
            }
        }
        const unsigned short* lK = smem[p];
        const unsigned short* lV = smem[p] + 4608;

        bf16x8 pf8[2][2];                      // [c2][nh] — P^T as x32 B-fragments
#pragma unroll
        for (int c2 = 0; c2 < 2; ++c2) {
            floatx4 sa[2][2];
#pragma unroll
            for (int AB = 0; AB < 2; ++AB) {
                sa[AB][0] = (floatx4){0.f,0.f,0.f,0.f};
                sa[AB][1] = (floatx4){0.f,0.f,0.f,0.f};
#pragma unroll
                for (int kc = 0; kc < 2; ++kc) {
                    bf16x8 kf = *(const bf16x8*)&lK[(c2*32 + AB*16 + lrow)*72 + kc*32 + quad*8];
                    sa[AB][0] = MFMA(kf, qf[0][kc], sa[AB][0]);
                    sa[AB][1] = MFMA(kf, qf[1][kc], sa[AB][1]);
                }
            }
#pragma unroll
            for (int nh = 0; nh < 2; ++nh) {
                floatx4 ea, eb;
#pragma unroll
                for (int i = 0; i < 4; ++i) { ea[i] = exp2f(sa[0][nh][i]); eb[i] = exp2f(sa[1][nh][i]); }
                ls[nh] += (ea[0]+ea[1]) + (ea[2]+ea[3]) + (eb[0]+eb[1]) + (eb[2]+eb[3]);
                pf8[c2][nh] = pack_bf16x8(ea, eb);
            }
        }
#pragma unroll
        for (int c2 = 0; c2 < 2; ++c2) {
#pragma unroll
            for (int dt = 0; dt < 4; ++dt) {
                bf16x8 vf = *(const bf16x8*)&lV[(dt*16 + lrow)*72 + c2*32 + quad*8];
                oacc[0][dt] = MFMA(vf, pf8[c2][0], oacc[0][dt]);
                oacc[1][dt] = MFMA(vf, pf8[c2][1], oacc[1][dt]);
            }
        }
        if (pre) {
#pragma unroll
            for (int r = 0; r < 2; ++r) {
                *(bf16x8*)&smem[p^1][krv[r]*72 + cgv[r]]        = pk[r];
                *(bf16x8*)&smem[p^1][4608 + mmv[r]*72 + cgv[r]] = pv[r];
            }
        }
        __syncthreads();
        p ^= 1;
    }
    // partial denominator (reduce over quads holding same n), raw (unnormalized)
#pragma unroll
    for (int nh = 0; nh < 2; ++nh) {
        ls[nh] += __shfl_xor(ls[nh], 16);
        ls[nh] += __shfl_xor(ls[nh], 32);
    }
    const size_t prow = (size_t)(chunk*16 + hb) * SEQ + qt * 128;
    if (lane < 16) {
        pol[prow + wid*32 + lrow]      = ls[0];
        pol[prow + wid*32 + 16 + lrow] = ls[1];
    }
    // stage partial O^T -> stF[n][d] then coalesced f32 write
    float* stF = (float*)&smem[0][0];          // [128][68] f32 = 34816 B
#pragma unroll
    for (int nh = 0; nh < 2; ++nh)
#pragma unroll
        for (int dt = 0; dt < 4; ++dt)
#pragma unroll
            for (int j = 0; j < 4; ++j)
                stF[(wid*32 + nh*16 + lrow)*68 + dt*16 + quad*4 + j] = oacc[nh][dt][j];
    __syncthreads();
#pragma unroll
    for (int i = 0; i < 4; ++i) {
        int c = i * 256 + t;
        int row = c >> 4, dp = c & 15;
        *(float4*)&poO[(prow + row) * HD + dp*4] = *(const float4*)&stF[row*68 + dp*4];
    }
}

// ---------------------------------------------------------------------------
// Combine m-chunk partials: attn'[hb][n][d] = (sum_c O_c) / (sum_c l_c).
// grid (16*SEQ*16/256) = 4096, block 256.
// ---------------------------------------------------------------------------
__global__ __launch_bounds__(256) void attn_combine(
        const float* __restrict__ poO, const float* __restrict__ pol,
        unsigned short* __restrict__ attnp)
{
    const int id = blockIdx.x * 256 + threadIdx.x;
    const int row = id >> 4, dp = id & 15;     // row = hb*SEQ + n
    const size_t CH = (size_t)16 * SEQ * HD;
    float4 a = *(const float4*)&poO[(size_t)row * HD + dp*4];
    float4 b = *(const float4*)&poO[CH + (size_t)row * HD + dp*4];
    float inv = 1.0f / (pol[row] + pol[row + 16*SEQ]);
    bf16x4 o = pack_bf16x4((a.x+b.x)*inv, (a.y+b.y)*inv, (a.z+b.z)*inv, (a.w+b.w)*inv);
    *(bf16x4*)&attnp[(size_t)row * HD + dp*4] = o;
}

// ---------------------------------------------------------------------------
// prep: column-permuted bf16 merge_w for attn' layout: W'[o][h*64+d]=W[o][d*4+h]
// ---------------------------------------------------------------------------
__global__ __launch_bounds__(256) void prep_wmerge(
        const float* __restrict__ W, unsigned short* __restrict__ Wp)
{
    int i = blockIdx.x * 256 + threadIdx.x;
    int o = i >> 8, cp = i & 255;
    Wp[i] = f2bf(W[(size_t)o * 256 + ((cp & 63) << 2) + (cp >> 6)]);
}

// ---------------------------------------------------------------------------
// GEMM (act x W^T), 64-pos tiles: out[pos][O] = act[pos][K] @ W[O][K]^T + bias
// mode 0: merge — act = attn' [hb][n][64], W = Wp bf16, O=K=256
// mode 1: mlp1  — K=512 (k<256: x f32 transpose; k>=256: msg), O=512,
//                 fused BN sum/sumsq atomics in epilogue.
// grid (O/128, NPOS/64), block 256.
// ---------------------------------------------------------------------------
__global__ __launch_bounds__(256) void gemm_act_w(
        const unsigned short* __restrict__ actA, const float* __restrict__ X,
        const float* __restrict__ Wf, const unsigned short* __restrict__ Wbf,
        const float* __restrict__ bias,
        unsigned short* __restrict__ out, int mode,
        float* __restrict__ sums, float* __restrict__ sumsq)
{
    __shared__ unsigned short lA[64][40];   // activations [pos][k]
    __shared__ unsigned short lB[128][40];  // W [o][k]
    const int t = threadIdx.x;
    const int lane = t & 63, wid = t >> 6;
    const int wm = wid >> 1, wn = wid & 1;
    const int lrow = lane & 15, quad = lane >> 4;
    const int o0 = blockIdx.x * 128;
    const int p0 = blockIdx.y * 64;
    const int b = p0 >> 12, n0 = p0 & (SEQ - 1);
    const int K = mode ? 512 : 256;
    const int O = mode ? 512 : 256;

    floatx4 acc[2][4];
#pragma unroll
    for (int i = 0; i < 2; ++i)
#pragma unroll
        for (int j = 0; j < 4; ++j) acc[i][j] = (floatx4){0.f,0.f,0.f,0.f};

    for (int k0 = 0; k0 < K; k0 += 32) {
        if (mode == 0) {
            int hq = k0 >> 6, d0 = k0 & 63;
            const size_t abase = ((size_t)(hq * BATCH + b) * SEQ + n0) * HD + d0;
            {
                int row = t >> 2, cg = (t & 3) * 8;
                *(bf16x8*)&lA[row][cg] = *(const bf16x8*)&actA[abase + (size_t)row * HD + cg];
            }
#pragma unroll
            for (int r = 0; r < 2; ++r) {
                int linear = r * 256 + t;
                int row = linear >> 2, cg = (linear & 3) * 8;
                *(bf16x8*)&lB[row][cg] = *(const bf16x8*)&Wbf[(size_t)(o0 + row) * 256 + k0 + cg];
            }
        } else {
            if (k0 < 256) {                     // x f32: transpose stage
#pragma unroll
                for (int r = 0; r < 2; ++r) {
                    int linear = r * 1024 + t * 4;
                    int ch = linear >> 6, nn = linear & 63;
                    const float4 x4 = *(const float4*)&X[((size_t)b * 256 + k0 + ch) * SEQ + n0 + nn];
                    lA[nn + 0][ch] = f2bf(x4.x);
                    lA[nn + 1][ch] = f2bf(x4.y);
                    lA[nn + 2][ch] = f2bf(x4.z);
                    lA[nn + 3][ch] = f2bf(x4.w);
                }
            } else {
                int row = t >> 2, cg = (t & 3) * 8;
                *(bf16x8*)&lA[row][cg] = *(const bf16x8*)&actA[(size_t)(p0 + row) * 256 + (k0 - 256) + cg];
            }
#pragma unroll
            for (int r = 0; r < 4; ++r) {       // stage W f32
                int linear = r * 1024 + t * 4;
                int row = linear >> 5, col = linear & 31;
                const float4 w4 = *(const float4*)&Wf[(size_t)(o0 + row) * K + k0 + col];
                ushortx4 s4 = { f2bf(w4.x), f2bf(w4.y), f2bf(w4.z), f2bf(w4.w) };
                *(ushortx4*)&lB[row][col] = s4;
            }
        }
        __syncthreads();
        bf16x8 aF[2], bF[4];
        const int kq = quad * 8;
#pragma unroll
        for (int mt = 0; mt < 2; ++mt)
            aF[mt] = *(const bf16x8*)&lA[wm*32 + mt*16 + lrow][kq];
#pragma unroll
        for (int nt = 0; nt < 4; ++nt)
            bF[nt] = *(const bf16x8*)&lB[wn*64 + nt*16 + lrow][kq];
#pragma unroll
        for (int mt = 0; mt < 2; ++mt)
#pragma unroll
            for (int nt = 0; nt < 4; ++nt)
                acc[mt][nt] = MFMA(aF[mt], bF[nt], acc[mt][nt]);
        __syncthreads();
    }
    // epilogue: D row = pos, col = o; out[pos][O] bf16 (+ fused BN stats, mode1)
#pragma unroll
    for (int nt = 0; nt < 4; ++nt) {
        int o = o0 + wn*64 + nt*16 + lrow;
        float bvv = bias[o];
        float s = 0.f, qs = 0.f;
#pragma unroll
        for (int mt = 0; mt < 2; ++mt)
#pragma unroll
            for (int j = 0; j < 4; ++j) {
                int pos = p0 + wm*32 + mt*16 + quad*4 + j;
                float val = acc[mt][nt][j] + bvv;
                out[(size_t)pos * O + o] = f2bf(val);
                s += val; qs += val * val;
            }
        if (mode == 1) {
            s  += __shfl_xor(s, 16);  s  += __shfl_xor(s, 32);
            qs += __shfl_xor(qs, 16); qs += __shfl_xor(qs, 32);
            if (lane < 16) {
                atomicAdd(&sums[o], s);
                atomicAdd(&sumsq[o], qs);
            }
        }
    }
}

__global__ __launch_bounds__(256) void bn_final(
        const float* __restrict__ sums, const float* __restrict__ sumsq,
        const float* __restrict__ gamma, const float* __restrict__ beta,
        float* __restrict__ scale, float* __restrict__ shift)
{
    int c = blockIdx.x * 256 + threadIdx.x;
    if (c < 512) {
        float mean = sums[c] * (1.0f / NPOS);
        float var  = sumsq[c] * (1.0f / NPOS) - mean * mean;
        float sc = gamma[c] * rsqrtf(var + 1e-5f);
        scale[c] = sc;
        shift[c] = beta[c] - mean * sc;
    }
}

// ---------------------------------------------------------------------------
// mlp2, 64-pos tiles: out[b][o][n] f32 = W[256][512] @ relu(bn(h1))^T + bias
// grid (2, NPOS/64), block 256.
// ---------------------------------------------------------------------------
__global__ __launch_bounds__(256) void gemm_mlp2(
        const float* __restrict__ W, const unsigned short* __restrict__ h1,
        const float* __restrict__ bias,
        const float* __restrict__ bnscale, const float* __restrict__ bnshift,
        float* __restrict__ out)
{
    __shared__ unsigned short lA[128][40];  // W [o][k]
    __shared__ unsigned short lB[64][40];   // act [pos][k]
    __shared__ float sSc[512], sSh[512];
    const int t = threadIdx.x;
    const int lane = t & 63, wid = t >> 6;
    const int wm = wid >> 1, wn = wid & 1;
    const int lrow = lane & 15, quad = lane >> 4;
    const int o0 = blockIdx.x * 128;
    const int p0 = blockIdx.y * 64;

    sSc[t] = bnscale[t];  sSc[t + 256] = bnscale[t + 256];
    sSh[t] = bnshift[t];  sSh[t + 256] = bnshift[t + 256];
    __syncthreads();

    floatx4 acc[4][2];
#pragma unroll
    for (int i = 0; i < 4; ++i)
#pragma unroll
        for (int j = 0; j < 2; ++j) acc[i][j] = (floatx4){0.f,0.f,0.f,0.f};

    for (int k0 = 0; k0 < 512; k0 += 32) {
#pragma unroll
        for (int r = 0; r < 4; ++r) {           // stage W
            int linear = r * 1024 + t * 4;
            int row = linear >> 5, col = linear & 31;
            const float4 w4 = *(const float4*)&W[(size_t)(o0 + row) * 512 + k0 + col];
            ushortx4 s4 = { f2bf(w4.x), f2bf(w4.y), f2bf(w4.z), f2bf(w4.w) };
            *(ushortx4*)&lA[row][col] = s4;
        }
        {                                        // stage h1 with BN+ReLU fused
            int row = t >> 2, cg = (t & 3) * 8;
            bf16x8 hv = *(const bf16x8*)&h1[(size_t)(p0 + row) * 512 + k0 + cg];
            unsigned short res[8];
#pragma unroll
            for (int i = 0; i < 8; ++i) {
                int c = k0 + cg + i;
                float f = bf2f((unsigned short)hv[i]);
                f = fmaxf(f * sSc[c] + sSh[c], 0.f);
                res[i] = f2bf(f);
            }
            *(bf16x8*)&lB[row][cg] = *(const bf16x8*)res;
        }
        __syncthreads();
        bf16x8 aF[4], bF[2];
        const int kq = quad * 8;
#pragma unroll
        for (int mt = 0; mt < 4; ++mt)
            aF[mt] = *(const bf16x8*)&lA[wm*64 + mt*16 + lrow][kq];
#pragma unroll
        for (int nt = 0; nt < 2; ++nt)
            bF[nt] = *(const bf16x8*)&lB[wn*32 + nt*16 + lrow][kq];
#pragma unroll
        for (int mt = 0; mt < 4; ++mt)
#pragma unroll
            for (int nt = 0; nt < 2; ++nt)
                acc[mt][nt] = MFMA(aF[mt], bF[nt], acc[mt][nt]);
        __syncthreads();
    }
    // epilogue: D row = o, col = pos; out[b][o][n] f32 (64B coalesced groups)
#pragma unroll
    for (int mt = 0; mt < 4; ++mt)
#pragma unroll
        for (int j = 0; j < 4; ++j) {
            int o = o0 + wm*64 + mt*16 + quad*4 + j;
            float bvv = bias[o];
#pragma unroll
            for (int nt = 0; nt < 2; ++nt) {
                int pos = p0 + wn*32 + nt*16 + lrow;
                int b = pos >> 12, n = pos & (SEQ - 1);
                out[((size_t)b * D_MODEL + o) * SEQ + n] = acc[mt][nt][j] + bvv;
            }
        }
}

// ---------------------------------------------------------------------------
extern "C" void kernel_launch(void* const* d_in, const int* in_sizes, int n_in,
                              void* d_out, int out_size, void* d_ws, size_t ws_size,
                              hipStream_t stream)
{
    (void)in_sizes; (void)n_in; (void)out_size; (void)ws_size;
    const float* x        = (const float*)d_in[0];
    const float* source   = (const float*)d_in[1];
    const float* pq_w     = (const float*)d_in[2];
    const float* pq_b     = (const float*)d_in[3];
    const float* pk_w     = (const float*)d_in[4];
    const float* pk_b     = (const float*)d_in[5];
    const float* pv_w     = (const float*)d_in[6];
    const float* pv_b     = (const float*)d_in[7];
    const float* merge_w  = (const float*)d_in[8];
    const float* merge_b  = (const float*)d_in[9];
    const float* mlp1_w   = (const float*)d_in[10];
    const float* mlp1_b   = (const float*)d_in[11];
    const float* bn_gamma = (const float*)d_in[12];
    const float* bn_beta  = (const float*)d_in[13];
    const float* mlp2_w   = (const float*)d_in[14];
    const float* mlp2_b   = (const float*)d_in[15];
    float* out = (float*)d_out;

    char* ws = (char*)d_ws;
    unsigned short* q    = (unsigned short*)(ws);                 //  8 MB [bh][n][64]
    unsigned short* kk   = (unsigned short*)(ws + (8ull  << 20)); //  8 MB [bh][m][64]
    unsigned short* v    = (unsigned short*)(ws + (16ull << 20)); //  8 MB [bh][64][m]
    unsigned short* attn = (unsigned short*)(ws + (24ull << 20)); //  8 MB [hb][n][64]
    unsigned short* msg  = (unsigned short*)(ws + (32ull << 20)); //  8 MB [pos][256]
    unsigned short* h1   = (unsigned short*)(ws + (40ull << 20)); // 16 MB [pos][512]
    float* bn_sum   = (float*)(ws + (56ull << 20));
    float* bn_sumsq = bn_sum + 512;
    float* bn_scale = bn_sum + 1024;
    float* bn_shift = bn_sum + 1536;
    unsigned short* wmp = (unsigned short*)(ws + (56ull << 20) + (64ull << 10)); // 128 KB
    float* poO = (float*)(ws + (58ull << 20));                    // 33.6 MB partial O
    float* pol = (float*)(ws + (92ull << 20));                    // 0.5 MB partial l

    hipMemsetAsync(bn_sum, 0, 1024 * sizeof(float), stream);

    prep_wmerge<<<dim3(256), 256, 0, stream>>>(merge_w, wmp);
    proj_qkv_all<<<dim3(6, SEQ/128, BATCH), 256, 0, stream>>>(
        pq_w, pq_b, pk_w, pk_b, pv_w, pv_b, x, source, q, kk, v);
    flash_attn<<<dim3(SEQ/128, 16*MCHUNKS), 256, 0, stream>>>(q, kk, v, poO, pol);
    attn_combine<<<dim3(16*SEQ*16/256), 256, 0, stream>>>(poO, pol, attn);
    gemm_act_w<<<dim3(2, NPOS/64), 256, 0, stream>>>(
        attn, nullptr, nullptr, wmp, merge_b, msg, 0, nullptr, nullptr);
    gemm_act_w<<<dim3(4, NPOS/64), 256, 0, stream>>>(
        msg, x, mlp1_w, nullptr, mlp1_b, h1, 1, bn_sum, bn_sumsq);
    bn_final<<<dim3(2), 256, 0, stream>>>(bn_sum, bn_sumsq, bn_gamma, bn_beta, bn_scale, bn_shift);
    gemm_mlp2<<<dim3(2, NPOS/64), 256, 0, stream>>>(mlp2_w, h1, mlp2_b, bn_scale, bn_shift, out);
}

// Round 5
// 311.409 us; speedup vs baseline: 1.2860x; 1.1041x over previous
//
#include <hip/hip_runtime.h>
#include <hip/hip_bf16.h>

#define D_MODEL 256
#define HEADS 4
#define HD 64
#define BATCH 4
#define SEQ 4096
#define NPOS (BATCH*SEQ)          // 16384 positions
#define SCALE_LOG2 0.18033688011112042f  // log2(e)/8, folded into q projection
#define MCHUNKS 2                 // flash m-split (partials add; no online max)

typedef __attribute__((ext_vector_type(4))) float floatx4;
typedef __attribute__((ext_vector_type(8))) short bf16x8;
typedef __attribute__((ext_vector_type(4))) short bf16x4;
typedef __attribute__((ext_vector_type(4))) unsigned short ushortx4;

__device__ __forceinline__ float bf2f(unsigned short b) {
    return __uint_as_float(((unsigned int)b) << 16);
}
__device__ __forceinline__ unsigned short f2bf(float f) {
    unsigned int u = __float_as_uint(f);
    return (unsigned short)((u + 0x7fffu + ((u >> 16) & 1u)) >> 16);
}
__device__ __forceinline__ bf16x4 pack_bf16x4(float a, float b, float c, float d) {
    __hip_bfloat162 lo = __float22bfloat162_rn(float2{a, b});
    __hip_bfloat162 hi = __float22bfloat162_rn(float2{c, d});
    union { __hip_bfloat162 h2[2]; bf16x4 v; } u;
    u.h2[0] = lo; u.h2[1] = hi;
    return u.v;
}
__device__ __forceinline__ bf16x8 pack_bf16x8(floatx4 a, floatx4 b) {
    union { bf16x4 h[2]; bf16x8 v; } u;
    u.h[0] = pack_bf16x4(a[0], a[1], a[2], a[3]);
    u.h[1] = pack_bf16x4(b[0], b[1], b[2], b[3]);
    return u.v;
}
#define MFMA(a,b,c) __builtin_amdgcn_mfma_f32_16x16x32_bf16((a),(b),(c),0,0,0)

// ---------------------------------------------------------------------------
// prep: (a) blocks [0,640): all weights f32->bf16 (merge W column-permuted
// for the attn' layout: W'[o][h*64+d] = W[o][d*4+h]).
//       (b) blocks [640,1152): transpose x/source [b][256][4096] f32 ->
// xT/srcT [b*4096+n][256] bf16 via 64x256 LDS tiles.
// ---------------------------------------------------------------------------
__global__ __launch_bounds__(256) void prep(
        const float* __restrict__ pq_w, const float* __restrict__ pk_w,
        const float* __restrict__ pv_w, const float* __restrict__ merge_w,
        const float* __restrict__ mlp1_w, const float* __restrict__ mlp2_w,
        const float* __restrict__ x, const float* __restrict__ src,
        unsigned short* __restrict__ wqb, unsigned short* __restrict__ wkb,
        unsigned short* __restrict__ wvb, unsigned short* __restrict__ wmp,
        unsigned short* __restrict__ w1b, unsigned short* __restrict__ w2b,
        unsigned short* __restrict__ xT, unsigned short* __restrict__ srcT)
{
    __shared__ unsigned short lT[64][264];
    const int t = threadIdx.x;
    const int bx = blockIdx.x;
    if (bx < 640) {
        int linear = bx * 1024 + t * 4;
        const float* srcW; unsigned short* dst; int off;
        if (linear < 65536)       { srcW = pq_w;   dst = wqb; off = 0; }
        else if (linear < 131072) { srcW = pk_w;   dst = wkb; off = 65536; }
        else if (linear < 196608) { srcW = pv_w;   dst = wvb; off = 131072; }
        else if (linear < 262144) {
            int i = linear - 196608;
            unsigned short s[4];
#pragma unroll
            for (int j = 0; j < 4; ++j) {
                int ii = i + j, o = ii >> 8, cp = ii & 255;
                s[j] = f2bf(merge_w[(size_t)o * 256 + ((cp & 63) << 2) + (cp >> 6)]);
            }
            *(ushortx4*)&wmp[i] = *(const ushortx4*)s;
            return;
        }
        else if (linear < 524288) { srcW = mlp1_w; dst = w1b; off = 262144; }
        else                      { srcW = mlp2_w; dst = w2b; off = 524288; }
        int i = linear - off;
        float4 w = *(const float4*)&srcW[i];
        ushortx4 s = { f2bf(w.x), f2bf(w.y), f2bf(w.z), f2bf(w.w) };
        *(ushortx4*)&dst[i] = s;
        return;
    }
    int z = bx - 640;
    const float* X = (z < 256) ? x : src;
    unsigned short* O = (z < 256) ? xT : srcT;
    int rem = z & 255;
    int b = rem >> 6, n0 = (rem & 63) * 64;
#pragma unroll
    for (int r = 0; r < 16; ++r) {
        int idx = r * 256 + t;
        int ch = idx >> 4, nnq = (idx & 15) * 4;
        float4 v4 = *(const float4*)&X[((size_t)b * 256 + ch) * SEQ + n0 + nnq];
        lT[nnq + 0][ch] = f2bf(v4.x);
        lT[nnq + 1][ch] = f2bf(v4.y);
        lT[nnq + 2][ch] = f2bf(v4.z);
        lT[nnq + 3][ch] = f2bf(v4.w);
    }
    __syncthreads();
#pragma unroll
    for (int r = 0; r < 8; ++r) {
        int idx = r * 256 + t;
        int row = idx >> 5, cg = (idx & 31) * 8;
        *(bf16x8*)&O[((size_t)b * SEQ + n0 + row) * 256 + cg] = *(const bf16x8*)&lT[row][cg];
    }
}

// ---------------------------------------------------------------------------
// Merged QKV projection (all-bf16 staging): grid (6, SEQ/128, B), block 256.
// blockIdx.x: mode = x>>1 (0=q,1=k,2=v), ob = (x&1)*128.
// q/k -> [bh][n][64] (q scaled by log2(e)/8); v -> [bh][64][m].
// ---------------------------------------------------------------------------
__global__ __launch_bounds__(256) void proj_qkv_all(
        const unsigned short* __restrict__ Wq, const float* __restrict__ bq,
        const unsigned short* __restrict__ Wk, const float* __restrict__ bk,
        const unsigned short* __restrict__ Wv, const float* __restrict__ bv,
        const unsigned short* __restrict__ xT, const unsigned short* __restrict__ srcT,
        unsigned short* __restrict__ qo, unsigned short* __restrict__ ko,
        unsigned short* __restrict__ vo)
{
    __shared__ unsigned short smem[128 * 80];   // lA(128x40)+lB(128x40); reused as stage[128][72]
    unsigned short (*lA)[40] = (unsigned short (*)[40])smem;
    unsigned short (*lB)[40] = (unsigned short (*)[40])(smem + 128 * 40);
    unsigned short (*stage)[72] = (unsigned short (*)[72])smem;
    const int t = threadIdx.x;
    const int lane = t & 63, wid = t >> 6;
    const int wm = wid >> 1, wn = wid & 1;
    const int lrow = lane & 15, quad = lane >> 4;
    const int mode = blockIdx.x >> 1;
    const int ob = (blockIdx.x & 1) * 128;
    const int n0 = blockIdx.y * 128;
    const int b  = blockIdx.z;
    const unsigned short* W  = (mode == 0) ? Wq : (mode == 1) ? Wk : Wv;
    const float* bias        = (mode == 0) ? bq : (mode == 1) ? bk : bv;
    const unsigned short* XT = (mode == 0) ? xT : srcT;
    unsigned short* out      = (mode == 0) ? qo : (mode == 1) ? ko : vo;

    floatx4 acc[4][4];
#pragma unroll
    for (int i = 0; i < 4; ++i)
#pragma unroll
        for (int j = 0; j < 4; ++j) acc[i][j] = (floatx4){0.f,0.f,0.f,0.f};

    for (int kc = 0; kc < 8; ++kc) {
        const int k0 = kc * 32;
#pragma unroll
        for (int r = 0; r < 2; ++r) {               // stage W -> lA (bf16)
            int linear = r * 256 + t;
            int row = linear >> 2, cg = (linear & 3) * 8;
            *(bf16x8*)&lA[row][cg] = *(const bf16x8*)&W[(size_t)(ob + row) * 256 + k0 + cg];
        }
#pragma unroll
        for (int r = 0; r < 2; ++r) {               // stage xT -> lB (bf16)
            int linear = r * 256 + t;
            int row = linear >> 2, cg = (linear & 3) * 8;
            *(bf16x8*)&lB[row][cg] = *(const bf16x8*)&XT[((size_t)b * SEQ + n0 + row) * 256 + k0 + cg];
        }
        __syncthreads();
        bf16x8 aF[4], bF[4];
        const int kq = quad * 8;
#pragma unroll
        for (int mt = 0; mt < 4; ++mt)
            aF[mt] = *(const bf16x8*)&lA[wm*64 + mt*16 + lrow][kq];
#pragma unroll
        for (int nt = 0; nt < 4; ++nt)
            bF[nt] = *(const bf16x8*)&lB[wn*64 + nt*16 + lrow][kq];
#pragma unroll
        for (int mt = 0; mt < 4; ++mt)
#pragma unroll
            for (int nt = 0; nt < 4; ++nt)
                acc[mt][nt] = MFMA(aF[mt], bF[nt], acc[mt][nt]);
        __syncthreads();
    }
    const float osc = (mode == 0) ? SCALE_LOG2 : 1.0f;
    if (mode == 2) {
        // v: direct epilogue, [bh][d][m]: 32B contiguous per quad-group
#pragma unroll
        for (int mt = 0; mt < 4; ++mt) {
#pragma unroll
            for (int j = 0; j < 4; ++j) {
                int o = ob + wm*64 + mt*16 + quad*4 + j;
                float bvv = bias[o];
                int d = o >> 2, h = o & 3;
#pragma unroll
                for (int nt = 0; nt < 4; ++nt) {
                    int n = n0 + wn*64 + nt*16 + lrow;
                    out[((size_t)(b*HEADS + h) * HD + d) * SEQ + n] = f2bf(acc[mt][nt][j] + bvv);
                }
            }
        }
        return;
    }
    // q/k: LDS-staged epilogue -> [bh][n][64] with 16B-contiguous chunks
    for (int half = 0; half < 2; ++half) {
        __syncthreads();
        if (wm == half) {
#pragma unroll
            for (int mt = 0; mt < 4; ++mt)
#pragma unroll
                for (int j = 0; j < 4; ++j) {
                    int o = ob + half*64 + mt*16 + quad*4 + j;
                    float bvv = bias[o];
                    int col = j*16 + mt*4 + quad;
#pragma unroll
                    for (int nt = 0; nt < 4; ++nt) {
                        int n = wn*64 + nt*16 + lrow;
                        stage[n][col] = f2bf((acc[mt][nt][j] + bvv) * osc);
                    }
                }
        }
        __syncthreads();
#pragma unroll
        for (int i = 0; i < 4; ++i) {
            int c = i * 256 + t;
            int n = c >> 3, h = (c >> 1) & 3, sub = c & 1;
            bf16x8 val = *(const bf16x8*)&stage[n][h*16 + sub*8];
            int d0 = (ob >> 2) + half*16 + sub*8;
            *(bf16x8*)&out[((size_t)(b*HEADS + h) * SEQ + n0 + n) * HD + d0] = val;
        }
    }
}

// ---------------------------------------------------------------------------
// Flash attention, transposed-softmax, m-split, double-buffered LDS.
// grid (SEQ/128, 16*MCHUNKS), block 256: wave = 32 q-rows; block covers 2048 m.
// Denominator l computed on the MFMA pipe: extra K=32 MFMA per (c2,nh) with an
// all-ones A-fragment gives l[n] in every lane (C-rows identical) — no VALU
// adds, no end shuffles. Partial O (f32) + partial l written per chunk.
// ---------------------------------------------------------------------------
__global__ __launch_bounds__(256, 4) void flash_attn(
        const unsigned short* __restrict__ q,
        const unsigned short* __restrict__ k,
        const unsigned short* __restrict__ v,
        float* __restrict__ poO, float* __restrict__ pol)
{
    __shared__ unsigned short smem[2][9216];   // per buf: lK 64x72 then lV 64x72
    const int t = threadIdx.x, lane = t & 63, wid = t >> 6;
    const int lrow = lane & 15, quad = lane >> 4;
    const int qt = blockIdx.x;
    const int bh = blockIdx.y & 15, chunk = blockIdx.y >> 4;
    const int hb = (bh & 3) * BATCH + (bh >> 2);   // h*BATCH+b for attn' order
    const int r0 = qt * 128 + wid * 32;

    bf16x8 qf[2][2];
#pragma unroll
    for (int nh = 0; nh < 2; ++nh) {
        const size_t base = ((size_t)bh * SEQ + r0 + nh*16 + lrow) * HD;
        qf[nh][0] = *(const bf16x8*)&q[base + quad * 8];
        qf[nh][1] = *(const bf16x8*)&q[base + 32 + quad * 8];
    }
    bf16x8 ones;
#pragma unroll
    for (int i = 0; i < 8; ++i) ones[i] = (short)0x3F80;  // bf16 1.0
    // staging coords (2 vectors per thread)
    int mmv[2], cgv[2], krv[2];
#pragma unroll
    for (int r = 0; r < 2; ++r) {
        int linear = r * 256 + t;
        int mm = linear >> 3, cg = (linear & 7) * 8;
        int c2 = mm >> 5, mp = mm & 31;
        mmv[r] = mm; cgv[r] = cg;
        krv[r] = (c2 << 5) + ((mp & 4) << 2) + ((mp >> 3) << 2) + (mp & 3);
    }
    const size_t kbase = ((size_t)bh * SEQ + chunk * (SEQ/MCHUNKS));
    const size_t vbase = (size_t)bh * HD;
    const int moff = chunk * (SEQ/MCHUNKS);
    const int NIT = SEQ / MCHUNKS / 64;

    floatx4 oacc[2][4], oaccL[2];
#pragma unroll
    for (int nh = 0; nh < 2; ++nh) {
        oaccL[nh] = (floatx4){0.f,0.f,0.f,0.f};
#pragma unroll
        for (int i = 0; i < 4; ++i) oacc[nh][i] = (floatx4){0.f,0.f,0.f,0.f};
    }

    // prologue: stage tile 0 into buf 0
    {
        bf16x8 pk[2], pv[2];
#pragma unroll
        for (int r = 0; r < 2; ++r) {
            pk[r] = *(const bf16x8*)&k[(kbase + mmv[r]) * HD + cgv[r]];
            pv[r] = *(const bf16x8*)&v[(vbase + mmv[r]) * SEQ + moff + cgv[r]];
        }
#pragma unroll
        for (int r = 0; r < 2; ++r) {
            *(bf16x8*)&smem[0][krv[r]*72 + cgv[r]]        = pk[r];
            *(bf16x8*)&smem[0][4608 + mmv[r]*72 + cgv[r]] = pv[r];
        }
    }
    __syncthreads();

    int p = 0;
#pragma unroll 1
    for (int it = 0; it < NIT; ++it) {
        bf16x8 pk[2], pv[2];
        const bool pre = (it + 1 < NIT);
        if (pre) {
            const int m1 = (it + 1) * 64;
#pragma unroll
            for (int r = 0; r < 2; ++r) {
                pk[r] = *(const bf16x8*)&k[(kbase + m1 + mmv[r]) * HD + cgv[r]];
                pv[r] = *(const bf16x8*)&v[(vbase + mmv[r]) * SEQ + moff + m1 + cgv[r]];
            }
        }
        const unsigned short* lK = smem[p];
        const unsigned short* lV = smem[p] + 4608;

        bf16x8 pf8[2][2];                      // [c2][nh] — P^T as x32 B-fragments
#pragma unroll
        for (int c2 = 0; c2 < 2; ++c2) {
            floatx4 sa[2][2];
#pragma unroll
            for (int AB = 0; AB < 2; ++AB) {
                sa[AB][0] = (floatx4){0.f,0.f,0.f,0.f};
                sa[AB][1] = (floatx4){0.f,0.f,0.f,0.f};
#pragma unroll
                for (int kc = 0; kc < 2; ++kc) {
                    bf16x8 kf = *(const bf16x8*)&lK[(c2*32 + AB*16 + lrow)*72 + kc*32 + quad*8];
                    sa[AB][0] = MFMA(kf, qf[0][kc], sa[AB][0]);
                    sa[AB][1] = MFMA(kf, qf[1][kc], sa[AB][1]);
                }
            }
#pragma unroll
            for (int nh = 0; nh < 2; ++nh) {
                floatx4 ea, eb;
#pragma unroll
                for (int i = 0; i < 4; ++i) { ea[i] = exp2f(sa[0][nh][i]); eb[i] = exp2f(sa[1][nh][i]); }
                pf8[c2][nh] = pack_bf16x8(ea, eb);
            }
        }
#pragma unroll
        for (int c2 = 0; c2 < 2; ++c2) {
            oaccL[0] = MFMA(ones, pf8[c2][0], oaccL[0]);
            oaccL[1] = MFMA(ones, pf8[c2][1], oaccL[1]);
#pragma unroll
            for (int dt = 0; dt < 4; ++dt) {
                bf16x8 vf = *(const bf16x8*)&lV[(dt*16 + lrow)*72 + c2*32 + quad*8];
                oacc[0][dt] = MFMA(vf, pf8[c2][0], oacc[0][dt]);
                oacc[1][dt] = MFMA(vf, pf8[c2][1], oacc[1][dt]);
            }
        }
        if (pre) {
#pragma unroll
            for (int r = 0; r < 2; ++r) {
                *(bf16x8*)&smem[p^1][krv[r]*72 + cgv[r]]        = pk[r];
                *(bf16x8*)&smem[p^1][4608 + mmv[r]*72 + cgv[r]] = pv[r];
            }
        }
        __syncthreads();
        p ^= 1;
    }
    // partial denominator: every lane holds l[n=lrow] in oaccL[nh][0]
    const size_t prow = (size_t)(chunk*16 + hb) * SEQ + qt * 128;
    if (lane < 16) {
        pol[prow + wid*32 + lrow]      = oaccL[0][0];
        pol[prow + wid*32 + 16 + lrow] = oaccL[1][0];
    }
    // stage partial O^T -> stF[n][d] then coalesced f32 write
    float* stF = (float*)&smem[0][0];          // [128][68] f32 = 34816 B
#pragma unroll
    for (int nh = 0; nh < 2; ++nh)
#pragma unroll
        for (int dt = 0; dt < 4; ++dt)
#pragma unroll
            for (int j = 0; j < 4; ++j)
                stF[(wid*32 + nh*16 + lrow)*68 + dt*16 + quad*4 + j] = oacc[nh][dt][j];
    __syncthreads();
#pragma unroll
    for (int i = 0; i < 4; ++i) {
        int c = i * 256 + t;
        int row = c >> 4, dp = c & 15;
        *(float4*)&poO[(prow + row) * HD + dp*4] = *(const float4*)&stF[row*68 + dp*4];
    }
}

// ---------------------------------------------------------------------------
// merge GEMM with FUSED partial-combine A-stage:
// msg[pos][256] = [(poO0+poO1)/l][pos][c'] @ Wp[256][256]^T + bias.
// grid (2, NPOS/64), block 256.
// ---------------------------------------------------------------------------
__global__ __launch_bounds__(256) void gemm_merge(
        const float* __restrict__ poO, const float* __restrict__ pol,
        const unsigned short* __restrict__ Wp, const float* __restrict__ bias,
        unsigned short* __restrict__ msg)
{
    __shared__ unsigned short lA[64][40];   // combined attn' [n][k-tile]
    __shared__ unsigned short lB[128][40];  // Wp [o][k]
    __shared__ float sInv[256];             // [h*64+n] inverse denominators
    const int t = threadIdx.x;
    const int lane = t & 63, wid = t >> 6;
    const int wm = wid >> 1, wn = wid & 1;
    const int lrow = lane & 15, quad = lane >> 4;
    const int o0 = blockIdx.x * 128;
    const int p0 = blockIdx.y * 64;
    const int b = p0 >> 12, n0 = p0 & (SEQ - 1);
    const size_t CH = (size_t)16 * SEQ * HD;

    {
        int h = t >> 6, nn = t & 63;
        int hb = h * BATCH + b;
        float l0 = pol[(size_t)hb * SEQ + n0 + nn];
        float l1 = pol[(size_t)(16 + hb) * SEQ + n0 + nn];
        sInv[t] = 1.0f / (l0 + l1);
    }
    __syncthreads();

    floatx4 acc[2][4];
#pragma unroll
    for (int i = 0; i < 2; ++i)
#pragma unroll
        for (int j = 0; j < 4; ++j) acc[i][j] = (floatx4){0.f,0.f,0.f,0.f};

    for (int k0 = 0; k0 < 256; k0 += 32) {
        const int h = k0 >> 6, d0 = k0 & 63, hb = h * BATCH + b;
        {
            int row = t >> 2, cg = (t & 3) * 8;
            const float* base = &poO[((size_t)hb * SEQ + n0 + row) * HD + d0 + cg];
            float4 a0 = *(const float4*)base;
            float4 a1 = *(const float4*)(base + 4);
            float4 c0 = *(const float4*)(base + CH);
            float4 c1 = *(const float4*)(base + CH + 4);
            float inv = sInv[h*64 + row];
            floatx4 v0 = {(a0.x+c0.x)*inv, (a0.y+c0.y)*inv, (a0.z+c0.z)*inv, (a0.w+c0.w)*inv};
            floatx4 v1 = {(a1.x+c1.x)*inv, (a1.y+c1.y)*inv, (a1.z+c1.z)*inv, (a1.w+c1.w)*inv};
            *(bf16x8*)&lA[row][cg] = pack_bf16x8(v0, v1);
        }
#pragma unroll
        for (int r = 0; r < 2; ++r) {
            int linear = r * 256 + t;
            int row = linear >> 2, cg = (linear & 3) * 8;
            *(bf16x8*)&lB[row][cg] = *(const bf16x8*)&Wp[(size_t)(o0 + row) * 256 + k0 + cg];
        }
        __syncthreads();
        bf16x8 aF[2], bF[4];
        const int kq = quad * 8;
#pragma unroll
        for (int mt = 0; mt < 2; ++mt)
            aF[mt] = *(const bf16x8*)&lA[wm*32 + mt*16 + lrow][kq];
#pragma unroll
        for (int nt = 0; nt < 4; ++nt)
            bF[nt] = *(const bf16x8*)&lB[wn*64 + nt*16 + lrow][kq];
#pragma unroll
        for (int mt = 0; mt < 2; ++mt)
#pragma unroll
            for (int nt = 0; nt < 4; ++nt)
                acc[mt][nt] = MFMA(aF[mt], bF[nt], acc[mt][nt]);
        __syncthreads();
    }
#pragma unroll
    for (int nt = 0; nt < 4; ++nt) {
        int o = o0 + wn*64 + nt*16 + lrow;
        float bvv = bias[o];
#pragma unroll
        for (int mt = 0; mt < 2; ++mt)
#pragma unroll
            for (int j = 0; j < 4; ++j) {
                int pos = p0 + wm*32 + mt*16 + quad*4 + j;
                msg[(size_t)pos * 256 + o] = f2bf(acc[mt][nt][j] + bvv);
            }
    }
}

// ---------------------------------------------------------------------------
// mlp1 GEMM (all-bf16): h1[pos][512] = [xT | msg][pos][512] @ W1[512][512]^T
// + bias, with fused BN sum/sumsq atomics. grid (4, NPOS/64), block 256.
// ---------------------------------------------------------------------------
__global__ __launch_bounds__(256) void gemm_mlp1(
        const unsigned short* __restrict__ xT, const unsigned short* __restrict__ msg,
        const unsigned short* __restrict__ W1, const float* __restrict__ bias,
        unsigned short* __restrict__ h1,
        float* __restrict__ sums, float* __restrict__ sumsq)
{
    __shared__ unsigned short lA[64][40];
    __shared__ unsigned short lB[128][40];
    const int t = threadIdx.x;
    const int lane = t & 63, wid = t >> 6;
    const int wm = wid >> 1, wn = wid & 1;
    const int lrow = lane & 15, quad = lane >> 4;
    const int o0 = blockIdx.x * 128;
    const int p0 = blockIdx.y * 64;

    floatx4 acc[2][4];
#pragma unroll
    for (int i = 0; i < 2; ++i)
#pragma unroll
        for (int j = 0; j < 4; ++j) acc[i][j] = (floatx4){0.f,0.f,0.f,0.f};

    for (int k0 = 0; k0 < 512; k0 += 32) {
        {
            const unsigned short* A = (k0 < 256) ? xT : msg;
            int row = t >> 2, cg = (t & 3) * 8;
            *(bf16x8*)&lA[row][cg] = *(const bf16x8*)&A[(size_t)(p0 + row) * 256 + (k0 & 255) + cg];
        }
#pragma unroll
        for (int r = 0; r < 2; ++r) {
            int linear = r * 256 + t;
            int row = linear >> 2, cg = (linear & 3) * 8;
            *(bf16x8*)&lB[row][cg] = *(const bf16x8*)&W1[(size_t)(o0 + row) * 512 + k0 + cg];
        }
        __syncthreads();
        bf16x8 aF[2], bF[4];
        const int kq = quad * 8;
#pragma unroll
        for (int mt = 0; mt < 2; ++mt)
            aF[mt] = *(const bf16x8*)&lA[wm*32 + mt*16 + lrow][kq];
#pragma unroll
        for (int nt = 0; nt < 4; ++nt)
            bF[nt] = *(const bf16x8*)&lB[wn*64 + nt*16 + lrow][kq];
#pragma unroll
        for (int mt = 0; mt < 2; ++mt)
#pragma unroll
            for (int nt = 0; nt < 4; ++nt)
                acc[mt][nt] = MFMA(aF[mt], bF[nt], acc[mt][nt]);
        __syncthreads();
    }
#pragma unroll
    for (int nt = 0; nt < 4; ++nt) {
        int o = o0 + wn*64 + nt*16 + lrow;
        float bvv = bias[o];
        float s = 0.f, qs = 0.f;
#pragma unroll
        for (int mt = 0; mt < 2; ++mt)
#pragma unroll
            for (int j = 0; j < 4; ++j) {
                int pos = p0 + wm*32 + mt*16 + quad*4 + j;
                float val = acc[mt][nt][j] + bvv;
                h1[(size_t)pos * 512 + o] = f2bf(val);
                s += val; qs += val * val;
            }
        s  += __shfl_xor(s, 16);  s  += __shfl_xor(s, 32);
        qs += __shfl_xor(qs, 16); qs += __shfl_xor(qs, 32);
        if (lane < 16) {
            atomicAdd(&sums[o], s);
            atomicAdd(&sumsq[o], qs);
        }
    }
}

// ---------------------------------------------------------------------------
// mlp2 (bf16 W, inline bn_final): out[b][o][n] f32 =
// W2[256][512] @ relu(bn(h1))^T + bias. grid (2, NPOS/64), block 256.
// ---------------------------------------------------------------------------
__global__ __launch_bounds__(256) void gemm_mlp2(
        const unsigned short* __restrict__ W2, const unsigned short* __restrict__ h1,
        const float* __restrict__ bias,
        const float* __restrict__ sums, const float* __restrict__ sumsq,
        const float* __restrict__ gamma, const float* __restrict__ beta,
        float* __restrict__ out)
{
    __shared__ unsigned short lA[128][40];  // W [o][k]
    __shared__ unsigned short lB[64][40];   // act [pos][k]
    __shared__ float sSc[512], sSh[512];
    const int t = threadIdx.x;
    const int lane = t & 63, wid = t >> 6;
    const int wm = wid >> 1, wn = wid & 1;
    const int lrow = lane & 15, quad = lane >> 4;
    const int o0 = blockIdx.x * 128;
    const int p0 = blockIdx.y * 64;

#pragma unroll
    for (int cc = 0; cc < 2; ++cc) {        // inline bn_final (redundant per block)
        int c = cc * 256 + t;
        float mean = sums[c] * (1.0f / NPOS);
        float var  = sumsq[c] * (1.0f / NPOS) - mean * mean;
        float sc = gamma[c] * rsqrtf(var + 1e-5f);
        sSc[c] = sc;
        sSh[c] = beta[c] - mean * sc;
    }
    __syncthreads();

    floatx4 acc[4][2];
#pragma unroll
    for (int i = 0; i < 4; ++i)
#pragma unroll
        for (int j = 0; j < 2; ++j) acc[i][j] = (floatx4){0.f,0.f,0.f,0.f};

    for (int k0 = 0; k0 < 512; k0 += 32) {
#pragma unroll
        for (int r = 0; r < 2; ++r) {           // stage W bf16
            int linear = r * 256 + t;
            int row = linear >> 2, cg = (linear & 3) * 8;
            *(bf16x8*)&lA[row][cg] = *(const bf16x8*)&W2[(size_t)(o0 + row) * 512 + k0 + cg];
        }
        {                                        // stage h1 with BN+ReLU fused
            int row = t >> 2, cg = (t & 3) * 8;
            bf16x8 hv = *(const bf16x8*)&h1[(size_t)(p0 + row) * 512 + k0 + cg];
            unsigned short res[8];
#pragma unroll
            for (int i = 0; i < 8; ++i) {
                int c = k0 + cg + i;
                float f = bf2f((unsigned short)hv[i]);
                f = fmaxf(f * sSc[c] + sSh[c], 0.f);
                res[i] = f2bf(f);
            }
            *(bf16x8*)&lB[row][cg] = *(const bf16x8*)res;
        }
        __syncthreads();
        bf16x8 aF[4], bF[2];
        const int kq = quad * 8;
#pragma unroll
        for (int mt = 0; mt < 4; ++mt)
            aF[mt] = *(const bf16x8*)&lA[wm*64 + mt*16 + lrow][kq];
#pragma unroll
        for (int nt = 0; nt < 2; ++nt)
            bF[nt] = *(const bf16x8*)&lB[wn*32 + nt*16 + lrow][kq];
#pragma unroll
        for (int mt = 0; mt < 4; ++mt)
#pragma unroll
            for (int nt = 0; nt < 2; ++nt)
                acc[mt][nt] = MFMA(aF[mt], bF[nt], acc[mt][nt]);
        __syncthreads();
    }
#pragma unroll
    for (int mt = 0; mt < 4; ++mt)
#pragma unroll
        for (int j = 0; j < 4; ++j) {
            int o = o0 + wm*64 + mt*16 + quad*4 + j;
            float bvv = bias[o];
#pragma unroll
            for (int nt = 0; nt < 2; ++nt) {
                int pos = p0 + wn*32 + nt*16 + lrow;
                int b = pos >> 12, n = pos & (SEQ - 1);
                out[((size_t)b * D_MODEL + o) * SEQ + n] = acc[mt][nt][j] + bvv;
            }
        }
}

// ---------------------------------------------------------------------------
extern "C" void kernel_launch(void* const* d_in, const int* in_sizes, int n_in,
                              void* d_out, int out_size, void* d_ws, size_t ws_size,
                              hipStream_t stream)
{
    (void)in_sizes; (void)n_in; (void)out_size; (void)ws_size;
    const float* x        = (const float*)d_in[0];
    const float* source   = (const float*)d_in[1];
    const float* pq_w     = (const float*)d_in[2];
    const float* pq_b     = (const float*)d_in[3];
    const float* pk_w     = (const float*)d_in[4];
    const float* pk_b     = (const float*)d_in[5];
    const float* pv_w     = (const float*)d_in[6];
    const float* pv_b     = (const float*)d_in[7];
    const float* merge_w  = (const float*)d_in[8];
    const float* merge_b  = (const float*)d_in[9];
    const float* mlp1_w   = (const float*)d_in[10];
    const float* mlp1_b   = (const float*)d_in[11];
    const float* bn_gamma = (const float*)d_in[12];
    const float* bn_beta  = (const float*)d_in[13];
    const float* mlp2_w   = (const float*)d_in[14];
    const float* mlp2_b   = (const float*)d_in[15];
    float* out = (float*)d_out;

    char* ws = (char*)d_ws;
    const size_t MB = 1ull << 20;
    unsigned short* xT   = (unsigned short*)(ws);             //  8 MB [pos][256]
    unsigned short* srcT = (unsigned short*)(ws + 8*MB);      //  8 MB [pos][256]
    unsigned short* q    = (unsigned short*)(ws + 16*MB);     //  8 MB [bh][n][64]
    unsigned short* kk   = (unsigned short*)(ws + 24*MB);     //  8 MB [bh][m][64]
    unsigned short* v    = (unsigned short*)(ws + 32*MB);     //  8 MB [bh][64][m]
    float* poO = (float*)(ws + 40*MB);                        // 32 MB partial O (2 chunks)
    unsigned short* h1 = (unsigned short*)(ws + 40*MB);       // 16 MB, reuses poO (dead by mlp1)
    float* pol = (float*)(ws + 72*MB);                        // 512 KB partial l
    unsigned short* wqb = (unsigned short*)(ws + 72*MB + 524288);
    unsigned short* wkb = wqb + 65536;
    unsigned short* wvb = wkb + 65536;
    unsigned short* wmp = wvb + 65536;
    unsigned short* w1b = wmp + 65536;                        // 512 KB
    unsigned short* w2b = w1b + 262144;                       // 256 KB
    float* bn_sum = (float*)(w2b + 131072);
    float* bn_sumsq = bn_sum + 512;
    unsigned short* msg = (unsigned short*)(ws + 76*MB);      //  8 MB [pos][256]

    hipMemsetAsync(bn_sum, 0, 1024 * sizeof(float), stream);

    prep<<<dim3(1152), 256, 0, stream>>>(
        pq_w, pk_w, pv_w, merge_w, mlp1_w, mlp2_w, x, source,
        wqb, wkb, wvb, wmp, w1b, w2b, xT, srcT);
    proj_qkv_all<<<dim3(6, SEQ/128, BATCH), 256, 0, stream>>>(
        wqb, pq_b, wkb, pk_b, wvb, pv_b, xT, srcT, q, kk, v);
    flash_attn<<<dim3(SEQ/128, 16*MCHUNKS), 256, 0, stream>>>(q, kk, v, poO, pol);
    gemm_merge<<<dim3(2, NPOS/64), 256, 0, stream>>>(poO, pol, wmp, merge_b, msg);
    gemm_mlp1<<<dim3(4, NPOS/64), 256, 0, stream>>>(xT, msg, w1b, mlp1_b, h1, bn_sum, bn_sumsq);
    gemm_mlp2<<<dim3(2, NPOS/64), 256, 0, stream>>>(
        w2b, h1, mlp2_b, bn_sum, bn_sumsq, bn_gamma, bn_beta, out);
}